// Round 7
// baseline (815.111 us; speedup 1.0000x reference)
//
#include <hip/hip_runtime.h>
#include <hip/hip_bf16.h>

#define Bn 32
#define Ln 1024
#define En 512
#define On 512

typedef __attribute__((ext_vector_type(8))) short bf16x8;
typedef __attribute__((ext_vector_type(4))) float f32x4;

__device__ __forceinline__ ushort f2bf(float x) {
    __hip_bfloat16 h = __float2bfloat16(x);
    return *reinterpret_cast<ushort*>(&h);
}
__device__ __forceinline__ float bf2f(ushort u) {
    __hip_bfloat16 h;
    *reinterpret_cast<ushort*>(&h) = u;
    return __bfloat162float(h);
}

__device__ __forceinline__ f32x4 mfma_bf16(bf16x8 a, bf16x8 b, f32x4 c) {
    return __builtin_amdgcn_mfma_f32_16x16x32_bf16(a, b, c, 0, 0, 0);
}

// ---------------------------------------------------------------------------
// Stage a 128x32 bf16 tile into linear LDS [128][32] via global_load_lds,
// 256 threads * 2 issues (used by the standalone GEMMs).
// ---------------------------------------------------------------------------
__device__ __forceinline__ void stage(ushort* dst, const ushort* src, size_t rstride) {
    const int tid = threadIdx.x;
#pragma unroll
    for (int cc = 0; cc < 2; ++cc) {
        const int c = tid + cc * 256;
        const ushort* g = src + (size_t)(c >> 2) * rstride + (c & 3) * 8;
        ushort* l = dst + ((size_t)(tid >> 6) * 64 + cc * 256) * 8;
        __builtin_amdgcn_global_load_lds(
            (const __attribute__((address_space(1))) unsigned int*)g,
            (__attribute__((address_space(3))) unsigned int*)l, 16, 0, 0);
    }
}

// ---------------------------------------------------------------------------
// Pipelined NT bf16 GEMM core (round-6 proven): 128x128 tile, BK=32, 256
// threads, double-buffered LDS + counted vmcnt + raw barriers.
// ---------------------------------------------------------------------------
template <bool SPLIT>
__device__ __forceinline__ void nt_core_pipe(const ushort* __restrict__ Ah,
                                             const ushort* __restrict__ Al,
                                             const ushort* __restrict__ Bh,
                                             const ushort* __restrict__ Bl,
                                             size_t astr, size_t bstr, int Kd,
                                             f32x4 (&acc)[4][4]) {
    constexpr int NTL = SPLIT ? 4 : 2;
    constexpr int LOADS = SPLIT ? 8 : 4;
    __shared__ ushort lds[2][NTL * 4096];

    const int tid = threadIdx.x;
    const int lane = tid & 63, wave = tid >> 6;
    const int wr = (wave >> 1) * 64, wc = (wave & 1) * 64;
    const int ln = lane & 15, kb = (lane >> 4) * 8;
    const int NT = Kd >> 5;

    auto stage_all = [&](int kt, int slot) {
        const int k0 = kt * 32;
        stage(&lds[slot][0], Ah + k0, astr);
        stage(&lds[slot][4096], Bh + k0, bstr);
        if constexpr (SPLIT) {
            stage(&lds[slot][8192], Al + k0, astr);
            stage(&lds[slot][12288], Bl + k0, bstr);
        }
    };

    stage_all(0, 0);
    stage_all(1, 1);
    asm volatile("s_waitcnt vmcnt(%0)" ::"i"(LOADS) : "memory");
    __builtin_amdgcn_sched_barrier(0);
    __builtin_amdgcn_s_barrier();

    for (int t = 0; t < NT; ++t) {
        __builtin_amdgcn_sched_barrier(0);
        const int cur = t & 1;
        const ushort* sAh = &lds[cur][0];
        const ushort* sBh = &lds[cur][4096];

        bf16x8 bh[4], bl[4];
#pragma unroll
        for (int n = 0; n < 4; ++n) {
            bh[n] = *(const bf16x8*)&sBh[(size_t)(wc + n * 16 + ln) * 32 + kb];
            if constexpr (SPLIT)
                bl[n] = *(const bf16x8*)&lds[cur][12288 + (size_t)(wc + n * 16 + ln) * 32 + kb];
        }
#pragma unroll
        for (int m = 0; m < 4; ++m) {
            bf16x8 ah = *(const bf16x8*)&sAh[(size_t)(wr + m * 16 + ln) * 32 + kb];
            if constexpr (SPLIT) {
                bf16x8 al = *(const bf16x8*)&lds[cur][8192 + (size_t)(wr + m * 16 + ln) * 32 + kb];
#pragma unroll
                for (int n = 0; n < 4; ++n) {
                    acc[m][n] = mfma_bf16(ah, bh[n], acc[m][n]);
                    acc[m][n] = mfma_bf16(ah, bl[n], acc[m][n]);
                    acc[m][n] = mfma_bf16(al, bh[n], acc[m][n]);
                }
            } else {
#pragma unroll
                for (int n = 0; n < 4; ++n) acc[m][n] = mfma_bf16(ah, bh[n], acc[m][n]);
            }
        }

        asm volatile("s_waitcnt lgkmcnt(0)" ::: "memory");
        __builtin_amdgcn_sched_barrier(0);
        __builtin_amdgcn_s_barrier();

        if (t + 2 < NT) {
            stage_all(t + 2, cur);
            asm volatile("s_waitcnt vmcnt(%0)" ::"i"(LOADS) : "memory");
            __builtin_amdgcn_sched_barrier(0);
            __builtin_amdgcn_s_barrier();
        } else if (t + 1 < NT) {
            asm volatile("s_waitcnt vmcnt(0)" ::: "memory");
            __builtin_amdgcn_sched_barrier(0);
            __builtin_amdgcn_s_barrier();
        }
    }
}

// ---------------------------------------------------------------------------
// W [E,O] fp32 -> per z: whi/wlo [n][k] bf16 (transposed), stride En.
// ---------------------------------------------------------------------------
__global__ __launch_bounds__(256) void convert_w(const float* __restrict__ Wq,
                                                 const float* __restrict__ Wk,
                                                 const float* __restrict__ Wv,
                                                 ushort* __restrict__ wsplit) {
    const int z = blockIdx.z;
    const float* W = (z == 0) ? Wq : (z == 1) ? Wk : Wv;
    ushort* hi = wsplit + (size_t)z * 2 * (En * On);
    ushort* lo = hi + En * On;
    __shared__ float tile[32][33];
    const int n0 = blockIdx.x * 32, k0 = blockIdx.y * 32;
    const int tid = threadIdx.x;
    const int r = tid >> 3, c4 = (tid & 7) * 4;
    float4 wv = *(const float4*)&W[(size_t)(k0 + r) * On + n0 + c4];
    tile[r][c4 + 0] = wv.x;
    tile[r][c4 + 1] = wv.y;
    tile[r][c4 + 2] = wv.z;
    tile[r][c4 + 3] = wv.w;
    __syncthreads();
    ushort4 hs, ls;
    ushort* hp = &hs.x;
    ushort* lp = &ls.x;
#pragma unroll
    for (int jj = 0; jj < 4; ++jj) {
        float f = tile[c4 + jj][r];
        ushort h = f2bf(f);
        hp[jj] = h;
        lp[jj] = f2bf(f - bf2f(h));
    }
    *(ushort4*)&hi[(size_t)(n0 + r) * En + k0 + c4] = hs;
    *(ushort4*)&lo[(size_t)(n0 + r) * En + k0 + c4] = ls;
}

// ---------------------------------------------------------------------------
// X [32768, 512] fp32 -> Xhi / Xlo [32768, 512] bf16
// ---------------------------------------------------------------------------
__global__ __launch_bounds__(256) void convert_x(const float* __restrict__ X,
                                                 ushort* __restrict__ Xhi,
                                                 ushort* __restrict__ Xlo) {
    const int g = blockIdx.x * 256 + threadIdx.x;
    const int row = g >> 6;
    const int k0 = (g & 63) * 8;
    const float* xp = X + (size_t)row * En + k0;
    float4 x0 = *(const float4*)xp;
    float4 x1 = *(const float4*)(xp + 4);
    float xs[8] = {x0.x, x0.y, x0.z, x0.w, x1.x, x1.y, x1.z, x1.w};
    bf16x8 hi, lo;
#pragma unroll
    for (int j = 0; j < 8; ++j) {
        ushort h = f2bf(xs[j]);
        hi[j] = (short)h;
        lo[j] = (short)f2bf(xs[j] - bf2f(h));
    }
    *(bf16x8*)(Xhi + (size_t)row * En + k0) = hi;
    *(bf16x8*)(Xlo + (size_t)row * En + k0) = lo;
}

// ---------------------------------------------------------------------------
// Pass 1a: Q,K = X * W^T. Split 3-term MFMA, K=512.
// ---------------------------------------------------------------------------
__global__ __launch_bounds__(256) void gemm_qkv(const ushort* __restrict__ Xhi,
                                                const ushort* __restrict__ Xlo,
                                                const ushort* __restrict__ wsplit,
                                                ushort* __restrict__ Qhi, ushort* __restrict__ Qlo,
                                                ushort* __restrict__ Khi, ushort* __restrict__ Klo) {
    const int n = blockIdx.x;
    const int xcd = n & 7;
    const int r = n >> 3;
    const int x = r & 7;
    const int y = (r >> 3) * 8 + xcd;
    const int row0 = y * 128;
    const int col0 = x * 128;
    const int z = col0 >> 9;
    const int wcol = col0 & 511;

    const ushort* Whi = wsplit + (size_t)z * 2 * (En * On) + (size_t)wcol * En;
    const ushort* Wlo = Whi + En * On;

    f32x4 acc[4][4] = {};
    nt_core_pipe<true>(Xhi + (size_t)row0 * En, Xlo + (size_t)row0 * En, Whi, Wlo, En, En, En, acc);

    const int tid = threadIdx.x;
    const int lane = tid & 63, wave = tid >> 6;
    const int wr = (wave >> 1) * 64, wc = (wave & 1) * 64;
    const int ln = lane & 15;

    ushort* oh = (z == 0) ? Qhi : Khi;
    ushort* ol = (z == 0) ? Qlo : Klo;
#pragma unroll
    for (int m = 0; m < 4; ++m)
#pragma unroll
        for (int nn = 0; nn < 4; ++nn)
#pragma unroll
            for (int rr = 0; rr < 4; ++rr) {
                const int gi = row0 + wr + m * 16 + (lane >> 4) * 4 + rr;
                const int gj = wcol + wc + nn * 16 + ln;
                const float v = acc[m][nn][rr];
                const ushort h = f2bf(v);
                const size_t idx = (size_t)gi * On + gj;
                oh[idx] = h;
                ol[idx] = f2bf(v - bf2f(h));
            }
}

// ---------------------------------------------------------------------------
// Pass 1b: V = X * Wv^T, plain bf16. Writes vt[b][o][l].
// ---------------------------------------------------------------------------
__global__ __launch_bounds__(256) void gemm_v(const ushort* __restrict__ Xhi,
                                              const ushort* __restrict__ wsplit,
                                              ushort* __restrict__ vt) {
    const int n = blockIdx.x;
    const int xcd = n & 7;
    const int c = n >> 3;
    const int x = c & 3;
    const int y = (c >> 2) * 8 + xcd;
    const int row0 = y * 128;
    const int col0 = x * 128;

    const ushort* Whi = wsplit + (size_t)2 * 2 * (En * On) + (size_t)col0 * En;

    f32x4 acc[4][4] = {};
    nt_core_pipe<false>(Xhi + (size_t)row0 * En, nullptr, Whi, nullptr, En, En, En, acc);

    const int tid = threadIdx.x;
    const int lane = tid & 63, wave = tid >> 6;
    const int wr = (wave >> 1) * 64, wc = (wave & 1) * 64;
    const int ln = lane & 15;

    const int b = row0 >> 10;
    const int lbase = row0 & (Ln - 1);
#pragma unroll
    for (int m = 0; m < 4; ++m)
#pragma unroll
        for (int nn = 0; nn < 4; ++nn) {
            const int gj = col0 + wc + nn * 16 + ln;
            const int l0 = lbase + wr + m * 16 + (lane >> 4) * 4;
            ushort4 u;
            u.x = f2bf(acc[m][nn][0]);
            u.y = f2bf(acc[m][nn][1]);
            u.z = f2bf(acc[m][nn][2]);
            u.w = f2bf(acc[m][nn][3]);
            *(ushort4*)(vt + ((size_t)b * On + gj) * Ln + l0) = u;
        }
}

// ---------------------------------------------------------------------------
// Fused scores+softmax+PV, flash-style, full-row softmax semantics.
// Block = 1 batch x 128 Q-rows, 512 threads = 8 waves (2M x 4N), 1 block/CU.
// grid 256: n = rt*32 + b  ->  XCD = b%8 (batch K/V pinned to one L2).
// ---------------------------------------------------------------------------
__global__ __launch_bounds__(512, 2) void fused_attn(
    const ushort* __restrict__ Qhi, const ushort* __restrict__ Qlo,
    const ushort* __restrict__ Khi, const ushort* __restrict__ Klo,
    const ushort* __restrict__ vt, const float* __restrict__ delta,
    const int* __restrict__ traj, float* __restrict__ out) {
    const int nblk = blockIdx.x;
    const int b = nblk & 31;
    const int rt = nblk >> 5;
    const int qr0 = rt * 128;
    const int t = traj[b];

    const int tid = threadIdx.x;
    const int lane = tid & 63;
    const int wave = tid >> 6;  // 0..7
    const int wm = wave >> 2;   // 0..1
    const int wn = wave & 3;    // 0..3
    const int ln = lane & 15;
    const int q4 = lane >> 4;
    const int kb = q4 * 8;

    __shared__ ushort qk[2][4][4096];  // [slot][{Qh,Kh,Ql,Kl}][128*32]  64KB
    __shared__ ushort plds[128][136];  // P tile bf16, padded              34.8KB
    __shared__ ushort vlds[512][40];   // V tile, padded (reg-staged)      40KB
    __shared__ float stats[128][4];    // per-row wave partials            2KB

    const size_t qbase = ((size_t)b * Ln + qr0) * On;
    const ushort* Qh = Qhi + qbase;
    const ushort* Ql = Qlo + qbase;

    f32x4 oacc[4][8] = {};
    float ml_m[4][4], ml_l[4][4];
#pragma unroll
    for (int m = 0; m < 4; ++m)
#pragma unroll
        for (int r = 0; r < 4; ++r) {
            ml_m[m][r] = -1e30f;
            ml_l[m][r] = 0.f;
        }

    for (int jt = 0; jt < 8; ++jt) {
        const int j0 = jt * 128;
        const size_t kbse = ((size_t)b * Ln + j0) * On;
        const ushort* Kh = Khi + kbse;
        const ushort* Kl = Klo + kbse;

        // ---------------- QK^T: counted-vmcnt dbuf, 16 ksteps ----------------
        f32x4 sacc[4][2] = {};
        auto stageqk = [&](int kt, int slot) {
            const int k0 = kt * 32;
            const int row = tid >> 2, col = (tid & 3) * 8;
            const size_t go = (size_t)row * On + k0 + col;
            const size_t lbase = (size_t)wave * 512;  // 64 chunks * 8 shorts
            __builtin_amdgcn_global_load_lds(
                (const __attribute__((address_space(1))) unsigned int*)(Qh + go),
                (__attribute__((address_space(3))) unsigned int*)&qk[slot][0][lbase], 16, 0, 0);
            __builtin_amdgcn_global_load_lds(
                (const __attribute__((address_space(1))) unsigned int*)(Kh + go),
                (__attribute__((address_space(3))) unsigned int*)&qk[slot][1][lbase], 16, 0, 0);
            __builtin_amdgcn_global_load_lds(
                (const __attribute__((address_space(1))) unsigned int*)(Ql + go),
                (__attribute__((address_space(3))) unsigned int*)&qk[slot][2][lbase], 16, 0, 0);
            __builtin_amdgcn_global_load_lds(
                (const __attribute__((address_space(1))) unsigned int*)(Kl + go),
                (__attribute__((address_space(3))) unsigned int*)&qk[slot][3][lbase], 16, 0, 0);
        };

        stageqk(0, 0);
        stageqk(1, 1);
        asm volatile("s_waitcnt vmcnt(4)" ::: "memory");
        __builtin_amdgcn_sched_barrier(0);
        __builtin_amdgcn_s_barrier();

        for (int ts = 0; ts < 16; ++ts) {
            __builtin_amdgcn_sched_barrier(0);
            const int cur = ts & 1;
            bf16x8 bh[2], bl[2];
#pragma unroll
            for (int nn = 0; nn < 2; ++nn) {
                const size_t bo = (size_t)(wn * 32 + nn * 16 + ln) * 32 + kb;
                bh[nn] = *(const bf16x8*)&qk[cur][1][bo];
                bl[nn] = *(const bf16x8*)&qk[cur][3][bo];
            }
#pragma unroll
            for (int m = 0; m < 4; ++m) {
                const size_t ao = (size_t)(wm * 64 + m * 16 + ln) * 32 + kb;
                bf16x8 ah = *(const bf16x8*)&qk[cur][0][ao];
                bf16x8 al = *(const bf16x8*)&qk[cur][2][ao];
#pragma unroll
                for (int nn = 0; nn < 2; ++nn) {
                    sacc[m][nn] = mfma_bf16(ah, bh[nn], sacc[m][nn]);
                    sacc[m][nn] = mfma_bf16(ah, bl[nn], sacc[m][nn]);
                    sacc[m][nn] = mfma_bf16(al, bh[nn], sacc[m][nn]);
                }
            }
            asm volatile("s_waitcnt lgkmcnt(0)" ::: "memory");
            __builtin_amdgcn_sched_barrier(0);
            __builtin_amdgcn_s_barrier();
            if (ts + 2 < 16) {
                stageqk(ts + 2, cur);
                asm volatile("s_waitcnt vmcnt(4)" ::: "memory");
                __builtin_amdgcn_sched_barrier(0);
                __builtin_amdgcn_s_barrier();
            } else if (ts + 1 < 16) {
                asm volatile("s_waitcnt vmcnt(0)" ::: "memory");
                __builtin_amdgcn_sched_barrier(0);
                __builtin_amdgcn_s_barrier();
            }
        }

        // ---------------- delta add ----------------
        const float* dbase = delta + (((size_t)b * Ln + qr0) * Ln + j0) * 4;
#pragma unroll
        for (int m = 0; m < 4; ++m)
#pragma unroll
            for (int nn = 0; nn < 2; ++nn)
#pragma unroll
                for (int r = 0; r < 4; ++r) {
                    const int ri = wm * 64 + m * 16 + q4 * 4 + r;
                    const int cj = wn * 32 + nn * 16 + ln;
                    const float4 dv = *(const float4*)(dbase + ((size_t)ri * Ln + cj) * 4);
                    sacc[m][nn][r] += (dv.x + dv.y) + (dv.z + dv.w);
                }

        // ---------------- row max (tile) ----------------
        float pm[4][4];
#pragma unroll
        for (int m = 0; m < 4; ++m)
#pragma unroll
            for (int r = 0; r < 4; ++r) pm[m][r] = fmaxf(sacc[m][0][r], sacc[m][1][r]);
#pragma unroll
        for (int off = 1; off <= 8; off <<= 1)
#pragma unroll
            for (int m = 0; m < 4; ++m)
#pragma unroll
                for (int r = 0; r < 4; ++r) pm[m][r] = fmaxf(pm[m][r], __shfl_xor(pm[m][r], off));
        if (ln == 0) {
#pragma unroll
            for (int m = 0; m < 4; ++m)
#pragma unroll
                for (int r = 0; r < 4; ++r) stats[wm * 64 + m * 16 + q4 * 4 + r][wn] = pm[m][r];
        }
        __syncthreads();

        float mnew[4][4], alpha[4][4];
#pragma unroll
        for (int m = 0; m < 4; ++m)
#pragma unroll
            for (int r = 0; r < 4; ++r) {
                const float4 sv = *(const float4*)&stats[wm * 64 + m * 16 + q4 * 4 + r][0];
                const float mx = fmaxf(fmaxf(sv.x, sv.y), fmaxf(sv.z, sv.w));
                mnew[m][r] = fmaxf(ml_m[m][r], mx);
                alpha[m][r] = __expf(ml_m[m][r] - mnew[m][r]);
                ml_m[m][r] = mnew[m][r];
            }
        __syncthreads();  // all waves done reading max stats

        // ---------------- p = exp(S - m), row sum ----------------
        float ps[4][4];
#pragma unroll
        for (int m = 0; m < 4; ++m)
#pragma unroll
            for (int r = 0; r < 4; ++r) {
                sacc[m][0][r] = __expf(sacc[m][0][r] - mnew[m][r]);
                sacc[m][1][r] = __expf(sacc[m][1][r] - mnew[m][r]);
                ps[m][r] = sacc[m][0][r] + sacc[m][1][r];
            }
#pragma unroll
        for (int off = 1; off <= 8; off <<= 1)
#pragma unroll
            for (int m = 0; m < 4; ++m)
#pragma unroll
                for (int r = 0; r < 4; ++r) ps[m][r] += __shfl_xor(ps[m][r], off);
        if (ln == 0) {
#pragma unroll
            for (int m = 0; m < 4; ++m)
#pragma unroll
                for (int r = 0; r < 4; ++r) stats[wm * 64 + m * 16 + q4 * 4 + r][wn] = ps[m][r];
        }
        __syncthreads();
#pragma unroll
        for (int m = 0; m < 4; ++m)
#pragma unroll
            for (int r = 0; r < 4; ++r) {
                const float4 sv = *(const float4*)&stats[wm * 64 + m * 16 + q4 * 4 + r][0];
                ml_l[m][r] = ml_l[m][r] * alpha[m][r] + ((sv.x + sv.y) + (sv.z + sv.w));
            }

        // ---------------- rescale O, write masked P (bf16) ----------------
#pragma unroll
        for (int m = 0; m < 4; ++m)
#pragma unroll
            for (int on = 0; on < 8; ++on)
#pragma unroll
                for (int r = 0; r < 4; ++r) oacc[m][on][r] *= alpha[m][r];
#pragma unroll
        for (int m = 0; m < 4; ++m)
#pragma unroll
            for (int nn = 0; nn < 2; ++nn)
#pragma unroll
                for (int r = 0; r < 4; ++r) {
                    const int ri = wm * 64 + m * 16 + q4 * 4 + r;
                    const int cj = wn * 32 + nn * 16 + ln;
                    const ushort pb = (j0 + cj < t) ? f2bf(sacc[m][nn][r]) : (ushort)0;
                    plds[ri][cj] = pb;
                }
        __syncthreads();  // P ready; stats reads done

        // ---------------- PV: 4 ksteps, V reg-staged to padded LDS ----------
        for (int ks = 0; ks < 4; ++ks) {
#pragma unroll
            for (int cc = 0; cc < 4; ++cc) {
                const int c = tid + cc * 512;
                const int row = c >> 2, col = (c & 3) * 8;
                const bf16x8 v =
                    *(const bf16x8*)(vt + ((size_t)b * On + row) * Ln + j0 + ks * 32 + col);
                *(bf16x8*)&vlds[row][col] = v;
            }
            __syncthreads();
            bf16x8 bfr[8];
#pragma unroll
            for (int on = 0; on < 8; ++on)
                bfr[on] = *(const bf16x8*)&vlds[wn * 128 + on * 16 + ln][kb];
#pragma unroll
            for (int m = 0; m < 4; ++m) {
                const bf16x8 a = *(const bf16x8*)&plds[wm * 64 + m * 16 + ln][ks * 32 + kb];
#pragma unroll
                for (int on = 0; on < 8; ++on) oacc[m][on] = mfma_bf16(a, bfr[on], oacc[m][on]);
            }
            __syncthreads();  // vlds free for next kstep / qk free for next tile
        }
    }

    // ---------------- epilogue: normalize, mask rows, store ----------------
    float inv[4][4];
#pragma unroll
    for (int m = 0; m < 4; ++m)
#pragma unroll
        for (int r = 0; r < 4; ++r) inv[m][r] = 1.0f / ml_l[m][r];
#pragma unroll
    for (int m = 0; m < 4; ++m)
#pragma unroll
        for (int on = 0; on < 8; ++on)
#pragma unroll
            for (int r = 0; r < 4; ++r) {
                const int gi = qr0 + wm * 64 + m * 16 + q4 * 4 + r;
                const int go = wn * 128 + on * 16 + ln;
                const float val = (gi < t) ? oacc[m][on][r] * inv[m][r] : 0.f;
                out[((size_t)b * Ln + gi) * On + go] = val;
            }
}

extern "C" void kernel_launch(void* const* d_in, const int* in_sizes, int n_in,
                              void* d_out, int out_size, void* d_ws, size_t ws_size,
                              hipStream_t stream) {
    const float* X = (const float*)d_in[0];      // [B, L, E]
    const float* delta = (const float*)d_in[1];  // [B, L, L, 4]
    const float* Wq = (const float*)d_in[2];     // [E, O]
    const float* Wk = (const float*)d_in[3];
    const float* Wv = (const float*)d_in[4];
    const int* traj = (const int*)d_in[5];       // [B]
    float* out = (float*)d_out;

    const size_t NE = (size_t)Bn * Ln * On;
    ushort* wsplit = (ushort*)d_ws;
    ushort* Xhi = wsplit + (size_t)3 * 2 * En * On;
    ushort* Xlo = Xhi + NE;
    ushort* Qhi = Xlo + NE;
    ushort* Qlo = Qhi + NE;
    ushort* Khi = Qlo + NE;
    ushort* Klo = Khi + NE;
    ushort* vt = Klo + NE;  // [B][O][L]

    convert_w<<<dim3(On / 32, En / 32, 3), 256, 0, stream>>>(Wq, Wk, Wv, wsplit);
    convert_x<<<dim3((Bn * Ln * 64) / 256), 256, 0, stream>>>(X, Xhi, Xlo);
    gemm_qkv<<<dim3(2048), 256, 0, stream>>>(Xhi, Xlo, wsplit, Qhi, Qlo, Khi, Klo);
    gemm_v<<<dim3(1024), 256, 0, stream>>>(Xhi, wsplit, vt);
    fused_attn<<<dim3(256), 512, 0, stream>>>(Qhi, Qlo, Khi, Klo, vt, delta, traj, out);
}

// Round 8
// 474.093 us; speedup vs baseline: 1.7193x; 1.7193x over previous
//
#include <hip/hip_runtime.h>
#include <hip/hip_bf16.h>

#define Bn 32
#define Ln 1024
#define En 512
#define On 512

typedef __attribute__((ext_vector_type(8))) short bf16x8;
typedef __attribute__((ext_vector_type(4))) float f32x4;

__device__ __forceinline__ ushort f2bf(float x) {
    __hip_bfloat16 h = __float2bfloat16(x);
    return *reinterpret_cast<ushort*>(&h);
}
__device__ __forceinline__ float bf2f(ushort u) {
    __hip_bfloat16 h;
    *reinterpret_cast<ushort*>(&h) = u;
    return __bfloat162float(h);
}

__device__ __forceinline__ f32x4 mfma_bf16(bf16x8 a, bf16x8 b, f32x4 c) {
    return __builtin_amdgcn_mfma_f32_16x16x32_bf16(a, b, c, 0, 0, 0);
}

// ---------------------------------------------------------------------------
// Stage a 128x32 bf16 tile into linear LDS [128][32] via global_load_lds.
// 256 threads * 2 issues * 16B = 8KB.
// ---------------------------------------------------------------------------
__device__ __forceinline__ void stage(ushort* dst, const ushort* src, size_t rstride) {
    const int tid = threadIdx.x;
#pragma unroll
    for (int cc = 0; cc < 2; ++cc) {
        const int c = tid + cc * 256;
        const ushort* g = src + (size_t)(c >> 2) * rstride + (c & 3) * 8;
        ushort* l = dst + ((size_t)(tid >> 6) * 64 + cc * 256) * 8;
        __builtin_amdgcn_global_load_lds(
            (const __attribute__((address_space(1))) unsigned int*)g,
            (__attribute__((address_space(3))) unsigned int*)l, 16, 0, 0);
    }
}

// ---------------------------------------------------------------------------
// Pipelined NT bf16 GEMM core (round-6 proven): 128x128 tile, BK=32, 256
// threads, double-buffered LDS + counted vmcnt + raw barriers.
// ---------------------------------------------------------------------------
template <bool SPLIT>
__device__ __forceinline__ void nt_core_pipe(const ushort* __restrict__ Ah,
                                             const ushort* __restrict__ Al,
                                             const ushort* __restrict__ Bh,
                                             const ushort* __restrict__ Bl,
                                             size_t astr, size_t bstr, int Kd,
                                             f32x4 (&acc)[4][4]) {
    constexpr int NTL = SPLIT ? 4 : 2;
    constexpr int LOADS = SPLIT ? 8 : 4;
    __shared__ ushort lds[2][NTL * 4096];

    const int tid = threadIdx.x;
    const int lane = tid & 63, wave = tid >> 6;
    const int wr = (wave >> 1) * 64, wc = (wave & 1) * 64;
    const int ln = lane & 15, kb = (lane >> 4) * 8;
    const int NT = Kd >> 5;

    auto stage_all = [&](int kt, int slot) {
        const int k0 = kt * 32;
        stage(&lds[slot][0], Ah + k0, astr);
        stage(&lds[slot][4096], Bh + k0, bstr);
        if constexpr (SPLIT) {
            stage(&lds[slot][8192], Al + k0, astr);
            stage(&lds[slot][12288], Bl + k0, bstr);
        }
    };

    stage_all(0, 0);
    stage_all(1, 1);
    asm volatile("s_waitcnt vmcnt(%0)" ::"i"(LOADS) : "memory");
    __builtin_amdgcn_sched_barrier(0);
    __builtin_amdgcn_s_barrier();

    for (int t = 0; t < NT; ++t) {
        __builtin_amdgcn_sched_barrier(0);
        const int cur = t & 1;
        const ushort* sAh = &lds[cur][0];
        const ushort* sBh = &lds[cur][4096];

        bf16x8 bh[4], bl[4];
#pragma unroll
        for (int n = 0; n < 4; ++n) {
            bh[n] = *(const bf16x8*)&sBh[(size_t)(wc + n * 16 + ln) * 32 + kb];
            if constexpr (SPLIT)
                bl[n] = *(const bf16x8*)&lds[cur][12288 + (size_t)(wc + n * 16 + ln) * 32 + kb];
        }
#pragma unroll
        for (int m = 0; m < 4; ++m) {
            bf16x8 ah = *(const bf16x8*)&sAh[(size_t)(wr + m * 16 + ln) * 32 + kb];
            if constexpr (SPLIT) {
                bf16x8 al = *(const bf16x8*)&lds[cur][8192 + (size_t)(wr + m * 16 + ln) * 32 + kb];
#pragma unroll
                for (int n = 0; n < 4; ++n) {
                    acc[m][n] = mfma_bf16(ah, bh[n], acc[m][n]);
                    acc[m][n] = mfma_bf16(ah, bl[n], acc[m][n]);
                    acc[m][n] = mfma_bf16(al, bh[n], acc[m][n]);
                }
            } else {
#pragma unroll
                for (int n = 0; n < 4; ++n) acc[m][n] = mfma_bf16(ah, bh[n], acc[m][n]);
            }
        }

        asm volatile("s_waitcnt lgkmcnt(0)" ::: "memory");
        __builtin_amdgcn_sched_barrier(0);
        __builtin_amdgcn_s_barrier();

        if (t + 2 < NT) {
            stage_all(t + 2, cur);
            asm volatile("s_waitcnt vmcnt(%0)" ::"i"(LOADS) : "memory");
            __builtin_amdgcn_sched_barrier(0);
            __builtin_amdgcn_s_barrier();
        } else if (t + 1 < NT) {
            asm volatile("s_waitcnt vmcnt(0)" ::: "memory");
            __builtin_amdgcn_sched_barrier(0);
            __builtin_amdgcn_s_barrier();
        }
    }
}

// ---------------------------------------------------------------------------
// W [E,O] fp32 -> per z: whi/wlo [n][k] bf16 (transposed), stride En.
// ---------------------------------------------------------------------------
__global__ __launch_bounds__(256) void convert_w(const float* __restrict__ Wq,
                                                 const float* __restrict__ Wk,
                                                 const float* __restrict__ Wv,
                                                 ushort* __restrict__ wsplit) {
    const int z = blockIdx.z;
    const float* W = (z == 0) ? Wq : (z == 1) ? Wk : Wv;
    ushort* hi = wsplit + (size_t)z * 2 * (En * On);
    ushort* lo = hi + En * On;
    __shared__ float tile[32][33];
    const int n0 = blockIdx.x * 32, k0 = blockIdx.y * 32;
    const int tid = threadIdx.x;
    const int r = tid >> 3, c4 = (tid & 7) * 4;
    float4 wv = *(const float4*)&W[(size_t)(k0 + r) * On + n0 + c4];
    tile[r][c4 + 0] = wv.x;
    tile[r][c4 + 1] = wv.y;
    tile[r][c4 + 2] = wv.z;
    tile[r][c4 + 3] = wv.w;
    __syncthreads();
    ushort4 hs, ls;
    ushort* hp = &hs.x;
    ushort* lp = &ls.x;
#pragma unroll
    for (int jj = 0; jj < 4; ++jj) {
        float f = tile[c4 + jj][r];
        ushort h = f2bf(f);
        hp[jj] = h;
        lp[jj] = f2bf(f - bf2f(h));
    }
    *(ushort4*)&hi[(size_t)(n0 + r) * En + k0 + c4] = hs;
    *(ushort4*)&lo[(size_t)(n0 + r) * En + k0 + c4] = ls;
}

// ---------------------------------------------------------------------------
// X [32768, 512] fp32 -> Xhi / Xlo [32768, 512] bf16
// ---------------------------------------------------------------------------
__global__ __launch_bounds__(256) void convert_x(const float* __restrict__ X,
                                                 ushort* __restrict__ Xhi,
                                                 ushort* __restrict__ Xlo) {
    const int g = blockIdx.x * 256 + threadIdx.x;
    const int row = g >> 6;
    const int k0 = (g & 63) * 8;
    const float* xp = X + (size_t)row * En + k0;
    float4 x0 = *(const float4*)xp;
    float4 x1 = *(const float4*)(xp + 4);
    float xs[8] = {x0.x, x0.y, x0.z, x0.w, x1.x, x1.y, x1.z, x1.w};
    bf16x8 hi, lo;
#pragma unroll
    for (int j = 0; j < 8; ++j) {
        ushort h = f2bf(xs[j]);
        hi[j] = (short)h;
        lo[j] = (short)f2bf(xs[j] - bf2f(h));
    }
    *(bf16x8*)(Xhi + (size_t)row * En + k0) = hi;
    *(bf16x8*)(Xlo + (size_t)row * En + k0) = lo;
}

// ---------------------------------------------------------------------------
// Pass 1a: Q,K = X * W^T. Split 3-term MFMA, K=512.
// ---------------------------------------------------------------------------
__global__ __launch_bounds__(256) void gemm_qkv(const ushort* __restrict__ Xhi,
                                                const ushort* __restrict__ Xlo,
                                                const ushort* __restrict__ wsplit,
                                                ushort* __restrict__ Qhi, ushort* __restrict__ Qlo,
                                                ushort* __restrict__ Khi, ushort* __restrict__ Klo) {
    const int n = blockIdx.x;
    const int xcd = n & 7;
    const int r = n >> 3;
    const int x = r & 7;
    const int y = (r >> 3) * 8 + xcd;
    const int row0 = y * 128;
    const int col0 = x * 128;
    const int z = col0 >> 9;
    const int wcol = col0 & 511;

    const ushort* Whi = wsplit + (size_t)z * 2 * (En * On) + (size_t)wcol * En;
    const ushort* Wlo = Whi + En * On;

    f32x4 acc[4][4] = {};
    nt_core_pipe<true>(Xhi + (size_t)row0 * En, Xlo + (size_t)row0 * En, Whi, Wlo, En, En, En, acc);

    const int tid = threadIdx.x;
    const int lane = tid & 63, wave = tid >> 6;
    const int wr = (wave >> 1) * 64, wc = (wave & 1) * 64;
    const int ln = lane & 15;

    ushort* oh = (z == 0) ? Qhi : Khi;
    ushort* ol = (z == 0) ? Qlo : Klo;
#pragma unroll
    for (int m = 0; m < 4; ++m)
#pragma unroll
        for (int nn = 0; nn < 4; ++nn)
#pragma unroll
            for (int rr = 0; rr < 4; ++rr) {
                const int gi = row0 + wr + m * 16 + (lane >> 4) * 4 + rr;
                const int gj = wcol + wc + nn * 16 + ln;
                const float v = acc[m][nn][rr];
                const ushort h = f2bf(v);
                const size_t idx = (size_t)gi * On + gj;
                oh[idx] = h;
                ol[idx] = f2bf(v - bf2f(h));
            }
}

// ---------------------------------------------------------------------------
// Pass 1b: V = X * Wv^T, plain bf16. Writes vt[b][o][l].
// ---------------------------------------------------------------------------
__global__ __launch_bounds__(256) void gemm_v(const ushort* __restrict__ Xhi,
                                              const ushort* __restrict__ wsplit,
                                              ushort* __restrict__ vt) {
    const int n = blockIdx.x;
    const int xcd = n & 7;
    const int c = n >> 3;
    const int x = c & 3;
    const int y = (c >> 2) * 8 + xcd;
    const int row0 = y * 128;
    const int col0 = x * 128;

    const ushort* Whi = wsplit + (size_t)2 * 2 * (En * On) + (size_t)col0 * En;

    f32x4 acc[4][4] = {};
    nt_core_pipe<false>(Xhi + (size_t)row0 * En, nullptr, Whi, nullptr, En, En, En, acc);

    const int tid = threadIdx.x;
    const int lane = tid & 63, wave = tid >> 6;
    const int wr = (wave >> 1) * 64, wc = (wave & 1) * 64;
    const int ln = lane & 15;

    const int b = row0 >> 10;
    const int lbase = row0 & (Ln - 1);
#pragma unroll
    for (int m = 0; m < 4; ++m)
#pragma unroll
        for (int nn = 0; nn < 4; ++nn) {
            const int gj = col0 + wc + nn * 16 + ln;
            const int l0 = lbase + wr + m * 16 + (lane >> 4) * 4;
            ushort4 u;
            u.x = f2bf(acc[m][nn][0]);
            u.y = f2bf(acc[m][nn][1]);
            u.z = f2bf(acc[m][nn][2]);
            u.w = f2bf(acc[m][nn][3]);
            *(ushort4*)(vt + ((size_t)b * On + gj) * Ln + l0) = u;
        }
}

// ---------------------------------------------------------------------------
// Pass 2: S[b] = Q[b]*K[b]^T (split 3-term) + sum_k delta -> fp32, PLUS
// per-row tile partials (m_tile, sumexp_tile) -> part[b][row][jt]{m,l}.
// grid 2048 linear; batch b -> XCD b%8.
// ---------------------------------------------------------------------------
__global__ __launch_bounds__(256) void gemm_scores(const ushort* __restrict__ Qhi,
                                                   const ushort* __restrict__ Qlo,
                                                   const ushort* __restrict__ Khi,
                                                   const ushort* __restrict__ Klo,
                                                   const float* __restrict__ delta,
                                                   float* __restrict__ S,
                                                   float* __restrict__ part) {
    const int n = blockIdx.x;
    const int xcd = n & 7;
    const int c = n >> 3;
    const int b = (c / 64) * 8 + xcd;
    const int xy = c % 64;
    const int col0 = (xy & 7) * 128;
    const int row0 = (xy >> 3) * 128;
    const int jt = xy & 7;

    const size_t abase = ((size_t)b * Ln + row0) * On;
    const size_t bbase = ((size_t)b * Ln + col0) * On;

    f32x4 acc[4][4] = {};
    nt_core_pipe<true>(Qhi + abase, Qlo + abase, Khi + bbase, Klo + bbase, On, On, On, acc);

    const int tid = threadIdx.x;
    const int lane = tid & 63, wave = tid >> 6;
    const int wr = (wave >> 1) * 64, wc = (wave & 1) * 64;
    const int ln = lane & 15, q4 = lane >> 4;

    __shared__ float rmax2[128][2], rsum2[128][2];

    // delta add + S write
#pragma unroll
    for (int m = 0; m < 4; ++m)
#pragma unroll
        for (int nn = 0; nn < 4; ++nn)
#pragma unroll
            for (int rr = 0; rr < 4; ++rr) {
                const int gi = row0 + wr + m * 16 + q4 * 4 + rr;
                const int gj = col0 + wc + nn * 16 + ln;
                const float4 dv = *(const float4*)(delta + (((size_t)b * Ln + gi) * Ln + gj) * 4);
                acc[m][nn][rr] += (dv.x + dv.y) + (dv.z + dv.w);
                S[((size_t)b * Ln + gi) * Ln + gj] = acc[m][nn][rr];
            }

    // tile-row max (half: 64 cols per col-wave)
#pragma unroll
    for (int m = 0; m < 4; ++m)
#pragma unroll
        for (int rr = 0; rr < 4; ++rr) {
            float mx = fmaxf(fmaxf(acc[m][0][rr], acc[m][1][rr]),
                             fmaxf(acc[m][2][rr], acc[m][3][rr]));
#pragma unroll
            for (int off = 1; off <= 8; off <<= 1) mx = fmaxf(mx, __shfl_xor(mx, off));
            if (ln == 0) rmax2[wr + m * 16 + q4 * 4 + rr][wave & 1] = mx;
        }
    __syncthreads();

    // tile-row sumexp with combined tile max
#pragma unroll
    for (int m = 0; m < 4; ++m)
#pragma unroll
        for (int rr = 0; rr < 4; ++rr) {
            const int rl = wr + m * 16 + q4 * 4 + rr;
            const float mt = fmaxf(rmax2[rl][0], rmax2[rl][1]);
            float se = __expf(acc[m][0][rr] - mt) + __expf(acc[m][1][rr] - mt) +
                       __expf(acc[m][2][rr] - mt) + __expf(acc[m][3][rr] - mt);
#pragma unroll
            for (int off = 1; off <= 8; off <<= 1) se += __shfl_xor(se, off);
            if (ln == 0) rsum2[rl][wave & 1] = se;
        }
    __syncthreads();

    if ((wave & 1) == 0 && ln == 0) {
#pragma unroll
        for (int m = 0; m < 4; ++m)
#pragma unroll
            for (int rr = 0; rr < 4; ++rr) {
                const int rl = wr + m * 16 + q4 * 4 + rr;
                const float mt = fmaxf(rmax2[rl][0], rmax2[rl][1]);
                const float lt = rsum2[rl][0] + rsum2[rl][1];
                float2* pp = (float2*)(part + (((size_t)b * Ln + row0 + rl) * 8 + jt) * 2);
                *pp = make_float2(mt, lt);
            }
    }
}

// ---------------------------------------------------------------------------
// Pass 3 (fused softmax+PV): out[b] = softmax(S)[b] * V[b].
// Prologue combines 8 tile-partials per row -> (m_row, 1/l_row). Main loop
// stages P = masked exp(S - m_row) bf16 (reg-staged) and V (gload_lds),
// K=1024, 32 ksteps; out scaled by 1/l_row, rows >= t zeroed.
// grid 1024 linear; batch b -> XCD b%8.
// ---------------------------------------------------------------------------
__global__ __launch_bounds__(256, 2) void gemm_pv(const float* __restrict__ S,
                                                  const float* __restrict__ part,
                                                  const ushort* __restrict__ vt,
                                                  const int* __restrict__ traj,
                                                  float* __restrict__ out) {
    const int n = blockIdx.x;
    const int xcd = n & 7;
    const int c = n >> 3;
    const int b = (c / 32) * 8 + xcd;
    const int xy = c % 32;
    const int col0 = (xy & 3) * 128;
    const int row0 = (xy >> 2) * 128;
    const int t = traj[b];

    const int tid = threadIdx.x;
    const int lane = tid & 63, wave = tid >> 6;
    const int wr = (wave >> 1) * 64, wc = (wave & 1) * 64;
    const int ln = lane & 15, kb = (lane >> 4) * 8;

    __shared__ ushort plds[128 * 32];  // 8KB
    __shared__ ushort vlds[128 * 32];  // 8KB
    __shared__ float rowm[128], rowinv[128];

    // ---- combine partials: m_row, 1/l_row ----
    if (tid < 128) {
        const float2* pp = (const float2*)(part + (((size_t)b * Ln + row0 + tid) * 8) * 2);
        float2 p[8];
#pragma unroll
        for (int j = 0; j < 8; ++j) p[j] = pp[j];
        float mr = p[0].x;
#pragma unroll
        for (int j = 1; j < 8; ++j) mr = fmaxf(mr, p[j].x);
        float lr = 0.f;
#pragma unroll
        for (int j = 0; j < 8; ++j) lr += p[j].y * __expf(p[j].x - mr);
        rowm[tid] = mr;
        rowinv[tid] = 1.0f / lr;
    }
    __syncthreads();

    const float* Sbase = S + ((size_t)b * Ln + row0) * Ln;

    f32x4 acc[4][4] = {};
    for (int ks = 0; ks < 32; ++ks) {
        const int j0 = ks * 32;
        // V tile via global_load_lds (async)
        stage(vlds, vt + ((size_t)b * On + col0) * Ln + j0, Ln);
        // P tile: reg-stage with exp + mask
#pragma unroll
        for (int cc = 0; cc < 2; ++cc) {
            const int ch = tid + cc * 256;
            const int row = ch >> 2, col8 = (ch & 3) * 8;
            const float* sp = Sbase + (size_t)row * Ln + j0 + col8;
            const float4 s0 = *(const float4*)sp;
            const float4 s1 = *(const float4*)(sp + 4);
            const float mr = rowm[row];
            const float ss[8] = {s0.x, s0.y, s0.z, s0.w, s1.x, s1.y, s1.z, s1.w};
            bf16x8 pb;
#pragma unroll
            for (int j = 0; j < 8; ++j)
                pb[j] = (short)((j0 + col8 + j < t) ? f2bf(__expf(ss[j] - mr)) : (ushort)0);
            *(bf16x8*)&plds[(size_t)row * 32 + col8] = pb;
        }
        __syncthreads();  // drains gload_lds (vmcnt) + ds_writes (lgkm)

        bf16x8 bfr[4];
#pragma unroll
        for (int nn = 0; nn < 4; ++nn)
            bfr[nn] = *(const bf16x8*)&vlds[(size_t)(wc + nn * 16 + ln) * 32 + kb];
#pragma unroll
        for (int m = 0; m < 4; ++m) {
            const bf16x8 a = *(const bf16x8*)&plds[(size_t)(wr + m * 16 + ln) * 32 + kb];
#pragma unroll
            for (int nn = 0; nn < 4; ++nn) acc[m][nn] = mfma_bf16(a, bfr[nn], acc[m][nn]);
        }
        __syncthreads();
    }

#pragma unroll
    for (int m = 0; m < 4; ++m)
#pragma unroll
        for (int nn = 0; nn < 4; ++nn)
#pragma unroll
            for (int rr = 0; rr < 4; ++rr) {
                const int rl = wr + m * 16 + (lane >> 4) * 4 + rr;
                const int gi = row0 + rl;
                const int gj = col0 + wc + nn * 16 + ln;
                const float val = (gi < t) ? acc[m][nn][rr] * rowinv[rl] : 0.f;
                out[((size_t)b * Ln + gi) * On + gj] = val;
            }
}

extern "C" void kernel_launch(void* const* d_in, const int* in_sizes, int n_in,
                              void* d_out, int out_size, void* d_ws, size_t ws_size,
                              hipStream_t stream) {
    const float* X = (const float*)d_in[0];      // [B, L, E]
    const float* delta = (const float*)d_in[1];  // [B, L, L, 4]
    const float* Wq = (const float*)d_in[2];     // [E, O]
    const float* Wk = (const float*)d_in[3];
    const float* Wv = (const float*)d_in[4];
    const int* traj = (const int*)d_in[5];       // [B]
    float* out = (float*)d_out;

    // ws layout (ushort units unless noted)
    const size_t NE = (size_t)Bn * Ln * On;  // 16.77M elements
    ushort* wsplit = (ushort*)d_ws;
    ushort* Xhi = wsplit + (size_t)3 * 2 * En * On;
    ushort* Xlo = Xhi + NE;
    ushort* Qhi = Xlo + NE;
    ushort* Qlo = Qhi + NE;
    ushort* Khi = Qlo + NE;
    ushort* Klo = Khi + NE;
    ushort* vt = Klo + NE;                    // [B][O][L]
    float* S = (float*)(vt + NE);             // [B][L][L] fp32
    float* part = S + (size_t)Bn * Ln * Ln;   // [B][L][8][2] fp32 (2MB)

    convert_w<<<dim3(On / 32, En / 32, 3), 256, 0, stream>>>(Wq, Wk, Wv, wsplit);
    convert_x<<<dim3((Bn * Ln * 64) / 256), 256, 0, stream>>>(X, Xhi, Xlo);
    gemm_qkv<<<dim3(2048), 256, 0, stream>>>(Xhi, Xlo, wsplit, Qhi, Qlo, Khi, Klo);
    gemm_v<<<dim3(1024), 256, 0, stream>>>(Xhi, wsplit, vt);
    gemm_scores<<<dim3(2048), 256, 0, stream>>>(Qhi, Qlo, Khi, Klo, delta, S, part);
    gemm_pv<<<dim3(1024), 256, 0, stream>>>(S, part, vt, traj, out);
}